// Round 6
// baseline (678.542 us; speedup 1.0000x reference)
//
#include <hip/hip_runtime.h>
#include <hip/hip_bf16.h>

typedef _Float16 f16;
typedef _Float16 f16x8 __attribute__((ext_vector_type(8)));
typedef _Float16 f16x4 __attribute__((ext_vector_type(4)));
typedef float    f32x4 __attribute__((ext_vector_type(4)));

#define MFMA16x16x32(a, b, c) __builtin_amdgcn_mfma_f32_16x16x32_f16(a, b, c, 0, 0, 0)

typedef __attribute__((address_space(1))) const void GASV;
typedef __attribute__((address_space(3))) void LASV;

#define WAIT_LGKM0 asm volatile("s_waitcnt lgkmcnt(0)" ::: "memory")
#define WAIT_VM6   asm volatile("s_waitcnt vmcnt(6)" ::: "memory")
#define WAIT_VM8   asm volatile("s_waitcnt vmcnt(8)" ::: "memory")

__device__ inline float gelu_f(float x) {
    float z = 0.79788456080286535588f * (x + 0.044715f * x * x * x);
    float e = __expf(2.0f * z);
    float t = 1.0f - 2.0f / (e + 1.0f);
    return 0.5f * x * (1.0f + t);
}

// ---------------------------------------------------------------------------
// Weight transpose + fp32 -> f16 convert:  in[K][N] f32  ->  out[N][K] f16
// ---------------------------------------------------------------------------
__global__ __launch_bounds__(256) void transpose_wt(const float* __restrict__ in,
                                                    f16* __restrict__ out,
                                                    int K, int N) {
    __shared__ float tile[32][33];
    int n0 = blockIdx.x * 32, k0 = blockIdx.y * 32;
    int tx = threadIdx.x & 31, ty = threadIdx.x >> 5;  // 32 x 8
#pragma unroll
    for (int i = 0; i < 32; i += 8)
        tile[ty + i][tx] = in[(size_t)(k0 + ty + i) * N + n0 + tx];
    __syncthreads();
#pragma unroll
    for (int i = 0; i < 32; i += 8)
        out[(size_t)(n0 + ty + i) * K + k0 + tx] = (f16)tile[tx][ty + i];
}

// ---------------------------------------------------------------------------
// LayerNorm (use_bias=False): fp32 in -> f16 out, row length 1024
// ---------------------------------------------------------------------------
__global__ __launch_bounds__(256) void ln_f16(const float* __restrict__ x,
                                              const float* __restrict__ g,
                                              f16* __restrict__ out) {
    int row = blockIdx.x, t = threadIdx.x;
    float4 v = ((const float4*)(x + (size_t)row * 1024))[t];
    float s  = v.x + v.y + v.z + v.w;
    float s2 = v.x * v.x + v.y * v.y + v.z * v.z + v.w * v.w;
#pragma unroll
    for (int off = 1; off < 64; off <<= 1) {
        s  += __shfl_xor(s, off);
        s2 += __shfl_xor(s2, off);
    }
    __shared__ float red[8];
    int w = t >> 6, lane = t & 63;
    if (lane == 0) { red[w] = s; red[4 + w] = s2; }
    __syncthreads();
    s  = red[0] + red[1] + red[2] + red[3];
    s2 = red[4] + red[5] + red[6] + red[7];
    float mean = s * (1.0f / 1024.0f);
    float var  = s2 * (1.0f / 1024.0f) - mean * mean;
    float r = rsqrtf(var + 1e-6f);
    float4 gv = ((const float4*)g)[t];
    f16x4 ov;
    ov[0] = (f16)((v.x - mean) * r * gv.x);
    ov[1] = (f16)((v.y - mean) * r * gv.y);
    ov[2] = (f16)((v.z - mean) * r * gv.z);
    ov[3] = (f16)((v.w - mean) * r * gv.w);
    *(f16x4*)(out + (size_t)row * 1024 + t * 4) = ov;
}

// ---------------------------------------------------------------------------
// 8-phase GEMM, deep-pipelined (tile t+2 staged during iter t).
// C[M,N] = A[M,K] @ Bt[N,K]^T, f16 in, fp32 acc. BN=256, BK=64,
// 512 threads = 8 waves (2 M x 4 N). BM=256 or 128. K, N compile-time.
// LDS: [2 bufs][AH+2 half-tiles][128x64 f16] + 16KB dummy tail region.
// Swizzle (3-bit): phys_slot = slot ^ (row & 7); staged via global_load_lds
// with inverse-swizzled global source (R4: conflicts = 0).
// Schedule per iter t (stages issued for tile t+2 => 4.5-5.5 phase lead,
// covers ~900cy HBM latency; R4's 2.5-phase lead stalled every vmcnt):
//   P0: read faL + fb[:][0,1];              MFMA faL x fb01
//   P1: read fb[:][2,3];                    MFMA faL x fb23
//   P2: read faH;     stage B0(t+2);        MFMA faH x fb01
//   P3:               stage B1,A*(t+2);     MFMA faH x fb23; vmcnt(N); barrier
// vmcnt invariant: queue at end P3(t) = [tile t+1: 8 loads][tile t+2: 8];
//   vmcnt(8) drains t+1 exactly (BM=128: 6+6, vmcnt(6)). Stages with
//   kt>=NT issue the SAME count into the dummy region, so the invariant
//   holds through the tail (R4 had a pass-through race at t=NT-2).
// EPI: 0 = f16 out; 1 = f16 gelu(acc+bias); 2 = f32 resid + rscale*acc;
//      3 = f32 resid + acc + bias
// ---------------------------------------------------------------------------
template <int BM, int EPI, int K, int N>
__global__ __launch_bounds__(512, 2) void gemm8(
    const f16* __restrict__ A, const f16* __restrict__ Bt,
    const float* __restrict__ bias, const float* __restrict__ resid,
    float* __restrict__ outF, f16* __restrict__ outH, float rscale) {
    static_assert(BM == 256 || BM == 128, "BM");
    constexpr int AH   = BM / 128;      // # A half-tiles
    constexpr int MREP = BM / 32;       // per-wave M fragments
    constexpr int MH   = MREP / 2;
    constexpr int NT   = K / 64;

    __shared__ __align__(16) f16 lds[2][AH + 2][128 * 64];
    __shared__ __align__(16) f16 dummyb[8192];   // 16KB tail-stage sink

    const int t512 = threadIdx.x;
    const int lane = t512 & 63, w = t512 >> 6;
    const int l15 = lane & 15, lg = lane >> 4;
    const int wr = w >> 2, wc = w & 3;   // 2 x 4 wave grid

    // bijective XCD swizzle (nwg % 8 == 0 for all our launches)
    const int nwg = gridDim.x;
    const int bid = blockIdx.x;
    const int swz = (bid & 7) * (nwg >> 3) + (bid >> 3);
    constexpr int nbn = N / 256;
    const int bm = swz / nbn, bn = swz % nbn;
    const int m0 = bm * BM, n0 = bn * 256;

    // wave's operand halves
    const int ahalf = (BM == 256) ? wr : 0;
    const int arow0 = (BM == 256) ? 0 : wr * 64;
    const int bhalf = AH + (wc >> 1);
    const int brow0 = (wc & 1) * 64;

    // ---- staging: one 16KB half-tile = 1024 16B chunks, 2 per thread ----
    auto stage = [&](int kt, int half) {
        const bool dum = (kt >= NT);
        f16* dst0 = dum ? dummyb : &lds[kt & 1][half][0];
        const bool isA = (half < AH);
        const f16* Mat = isA ? A : Bt;
        const int rb = isA ? (m0 + half * 128) : (n0 + (half - AH) * 128);
#pragma unroll
        for (int u = 0; u < 2; ++u) {
            int c = u * 512 + t512;
            // inverse-swizzled source chunk (involution, matches ldfrag)
            int cs = c ^ ((c >> 3) & 7);
            const f16* src = dum ? (A + (size_t)(c & 511) * 8)
                                 : (Mat + (size_t)(rb + (cs >> 3)) * K + kt * 64 + (cs & 7) * 8);
            __builtin_amdgcn_global_load_lds((GASV*)src, (LASV*)(dst0 + c * 8), 16, 0, 0);
        }
    };
    // swizzled frag read: logical (half, row-in-half, 16B slot)
    auto ldfrag = [&](int cur, int half, int rh, int s) -> f16x8 {
        int ps = s ^ (rh & 7);
        return *(const f16x8*)(&lds[cur][half][0] + rh * 64 + ps * 8);
    };

    f32x4 acc[MREP][4] = {};
    f16x8 faL[2][MH], faH[2][MH], fb[2][4];

    // ---- prologue: tiles 0 and 1 fully staged; drain tile 0 ----
#pragma unroll
    for (int h = 0; h < AH + 2; ++h) stage(0, h);
#pragma unroll
    for (int h = 0; h < AH + 2; ++h) stage(1, h);
    if (BM == 256) { WAIT_VM8; } else { WAIT_VM6; }
    __builtin_amdgcn_s_barrier();

    for (int t = 0; t < NT; ++t) {
        const int cur = t & 1;
        // ---------------- P0: read faL + fb[:][0,1] ----------------
#pragma unroll
        for (int ks = 0; ks < 2; ++ks) {
#pragma unroll
            for (int i = 0; i < MH; ++i) {
                int rh = arow0 + i * 16 + l15;
                faL[ks][i] = ldfrag(cur, ahalf, rh, ks * 4 + lg);
            }
#pragma unroll
            for (int j = 0; j < 2; ++j) {
                int rh = brow0 + j * 16 + l15;
                fb[ks][j] = ldfrag(cur, bhalf, rh, ks * 4 + lg);
            }
        }
        __builtin_amdgcn_s_barrier();
        WAIT_LGKM0;
        __builtin_amdgcn_s_setprio(1);
#pragma unroll
        for (int i = 0; i < MH; ++i)
#pragma unroll
            for (int j = 0; j < 2; ++j)
#pragma unroll
                for (int ks = 0; ks < 2; ++ks)
                    acc[i][j] = MFMA16x16x32(faL[ks][i], fb[ks][j], acc[i][j]);
        __builtin_amdgcn_s_setprio(0);
        __builtin_amdgcn_s_barrier();
        // ---------------- P1: read fb[:][2,3] ----------------
#pragma unroll
        for (int ks = 0; ks < 2; ++ks)
#pragma unroll
            for (int j = 2; j < 4; ++j) {
                int rh = brow0 + j * 16 + l15;
                fb[ks][j] = ldfrag(cur, bhalf, rh, ks * 4 + lg);
            }
        __builtin_amdgcn_s_barrier();
        WAIT_LGKM0;
        __builtin_amdgcn_s_setprio(1);
#pragma unroll
        for (int i = 0; i < MH; ++i)
#pragma unroll
            for (int j = 0; j < 2; ++j)
#pragma unroll
                for (int ks = 0; ks < 2; ++ks)
                    acc[i][2 + j] = MFMA16x16x32(faL[ks][i], fb[ks][2 + j], acc[i][2 + j]);
        __builtin_amdgcn_s_setprio(0);
        __builtin_amdgcn_s_barrier();
        // ---------------- P2: read faH; stage B0(t+2) ----------------
#pragma unroll
        for (int ks = 0; ks < 2; ++ks)
#pragma unroll
            for (int i = 0; i < MH; ++i) {
                int rh = arow0 + (MH + i) * 16 + l15;
                faH[ks][i] = ldfrag(cur, ahalf, rh, ks * 4 + lg);
            }
        stage(t + 2, AH + 0);
        __builtin_amdgcn_s_barrier();
        WAIT_LGKM0;
        __builtin_amdgcn_s_setprio(1);
#pragma unroll
        for (int i = 0; i < MH; ++i)
#pragma unroll
            for (int j = 0; j < 2; ++j)
#pragma unroll
                for (int ks = 0; ks < 2; ++ks)
                    acc[MH + i][j] = MFMA16x16x32(faH[ks][i], fb[ks][j], acc[MH + i][j]);
        __builtin_amdgcn_s_setprio(0);
        __builtin_amdgcn_s_barrier();
        // ---------------- P3: stage B1(t+2), A*(t+2) ----------------
        stage(t + 2, AH + 1);
#pragma unroll
        for (int h = 0; h < AH; ++h) stage(t + 2, h);
        __builtin_amdgcn_s_barrier();
        WAIT_LGKM0;
        __builtin_amdgcn_s_setprio(1);
#pragma unroll
        for (int i = 0; i < MH; ++i)
#pragma unroll
            for (int j = 0; j < 2; ++j)
#pragma unroll
                for (int ks = 0; ks < 2; ++ks)
                    acc[MH + i][2 + j] = MFMA16x16x32(faH[ks][i], fb[ks][2 + j], acc[MH + i][2 + j]);
        __builtin_amdgcn_s_setprio(0);
        if (BM == 256) { WAIT_VM8; } else { WAIT_VM6; }
        __builtin_amdgcn_s_barrier();
    }

    // ---- epilogue ----
#pragma unroll
    for (int mi = 0; mi < MREP; ++mi) {
#pragma unroll
        for (int ni = 0; ni < 4; ++ni) {
            int colL = n0 + wc * 64 + ni * 16 + l15;
#pragma unroll
            for (int j = 0; j < 4; ++j) {
                int rowL = m0 + ((BM == 256) ? wr * 128 : wr * 64) + mi * 16 + lg * 4 + j;
                size_t idx = (size_t)rowL * N + colL;
                float vv = acc[mi][ni][j];
                if constexpr (EPI == 0) {
                    outH[idx] = (f16)vv;
                } else if constexpr (EPI == 1) {
                    vv += bias[colL];
                    outH[idx] = (f16)gelu_f(vv);
                } else if constexpr (EPI == 2) {
                    outF[idx] = resid[idx] + rscale * vv;
                } else {
                    outF[idx] = resid[idx] + vv + bias[colL];
                }
            }
        }
    }
}

// ---------------------------------------------------------------------------
// Fused attention: one block per (b,h). Full K (swizzled) + V^T (swizzled)
// resident in LDS. qkv packed [8192][3072]: q at col 0, k at 1024, v at 2048.
// ---------------------------------------------------------------------------
__global__ __launch_bounds__(256) void attn_f16(const f16* __restrict__ qkv,
                                                int ld, f16* __restrict__ o) {
    __shared__ __align__(16) f16 Ks[512 * 64];
    __shared__ __align__(16) f16 Vt[64 * 512];
    __shared__ __align__(16) f16 Ps[4][16 * 32];

    const int t = threadIdx.x, lane = t & 63, w = t >> 6;
    const int l15 = lane & 15, lg = lane >> 4;
    const int bh = blockIdx.x, b = bh >> 4, h = bh & 15;
    const f16* qg = qkv + (size_t)(b * 512) * ld + h * 64;
    const f16* kg = qg + 1024;
    const f16* vg = qg + 2048;

#pragma unroll
    for (int i = 0; i < 16; ++i) {
        int c = i * 256 + t, r = c >> 3, s = c & 7;
        f16x8 val = *(const f16x8*)(kg + (size_t)r * ld + s * 8);
        *(f16x8*)((char*)Ks + r * 128 + ((s ^ (r & 7)) * 16)) = val;
    }
#pragma unroll
    for (int i = 0; i < 16; ++i) {
        int c = i * 256 + t, r = c >> 3, s = c & 7;
        f16x8 val = *(const f16x8*)(vg + (size_t)r * ld + s * 8);
#pragma unroll
        for (int dd = 0; dd < 8; ++dd) {
            int d = s * 8 + dd;
            *(f16*)((char*)Vt + d * 1024 + ((r * 2) ^ ((d & 7) << 4))) = val[dd];
        }
    }
    __syncthreads();

    for (int it = 0; it < 8; ++it) {
        int q0 = it * 64 + w * 16;
        f16x8 aq[2];
#pragma unroll
        for (int kk = 0; kk < 2; ++kk)
            aq[kk] = *(const f16x8*)(qg + (size_t)(q0 + l15) * ld + kk * 32 + lg * 8);

        f32x4 sc[32] = {};
#pragma unroll
        for (int jt = 0; jt < 32; ++jt) {
#pragma unroll
            for (int kk = 0; kk < 2; ++kk) {
                int row = jt * 16 + l15;
                f16x8 bk = *(const f16x8*)((char*)Ks + row * 128 + (((kk * 4 + lg) ^ (l15 & 7)) * 16));
                sc[jt] = MFMA16x16x32(aq[kk], bk, sc[jt]);
            }
        }

        float inv_sum[4];
#pragma unroll
        for (int r4 = 0; r4 < 4; ++r4) {
            float m = sc[0][r4];
#pragma unroll
            for (int jt = 1; jt < 32; ++jt) m = fmaxf(m, sc[jt][r4]);
#pragma unroll
            for (int off = 1; off < 16; off <<= 1) m = fmaxf(m, __shfl_xor(m, off));
            float sum = 0.0f;
#pragma unroll
            for (int jt = 0; jt < 32; ++jt) {
                float p = __expf((sc[jt][r4] - m) * 0.125f);
                sc[jt][r4] = p;
                sum += p;
            }
#pragma unroll
            for (int off = 1; off < 16; off <<= 1) sum += __shfl_xor(sum, off);
            inv_sum[r4] = 1.0f / sum;
        }

        f32x4 oa[4] = {};
        f16* myPs = &Ps[w][0];
#pragma unroll
        for (int u = 0; u < 16; ++u) {
#pragma unroll
            for (int half = 0; half < 2; ++half) {
                int jt = 2 * u + half;
#pragma unroll
                for (int r4 = 0; r4 < 4; ++r4) {
                    int row = lg * 4 + r4;
                    int colb = (half * 16 + l15) * 2;
                    *(f16*)((char*)myPs + row * 64 + (colb ^ (((row >> 1) & 3) << 4))) =
                        (f16)sc[jt][r4];
                }
            }
            f16x8 pa = *(const f16x8*)((char*)myPs + l15 * 64 + ((lg ^ ((l15 >> 1) & 3)) * 16));
#pragma unroll
            for (int ct = 0; ct < 4; ++ct) {
                int vrow = ct * 16 + l15;
                f16x8 bv = *(const f16x8*)((char*)Vt + vrow * 1024 + (((u * 4 + lg) ^ (vrow & 7)) * 16));
                oa[ct] = MFMA16x16x32(pa, bv, oa[ct]);
            }
        }

#pragma unroll
        for (int ct = 0; ct < 4; ++ct)
#pragma unroll
            for (int j = 0; j < 4; ++j) {
                int row = q0 + lg * 4 + j;
                int col = h * 64 + ct * 16 + l15;
                o[(size_t)(b * 512 + row) * 1024 + col] = (f16)(oa[ct][j] * inv_sum[j]);
            }
    }
}

// ---------------------------------------------------------------------------
extern "C" void kernel_launch(void* const* d_in, const int* in_sizes, int n_in,
                              void* d_out, int out_size, void* d_ws, size_t ws_size,
                              hipStream_t stream) {
    (void)in_sizes; (void)n_in; (void)out_size; (void)ws_size;
    const float* x   = (const float*)d_in[0];
    const float* wq  = (const float*)d_in[1];
    const float* wk  = (const float*)d_in[2];
    const float* wv  = (const float*)d_in[3];
    const float* wo  = (const float*)d_in[4];
    const float* ln1 = (const float*)d_in[5];
    const float* ln2 = (const float*)d_in[6];
    const float* w1  = (const float*)d_in[7];
    const float* b1  = (const float*)d_in[8];
    const float* w2  = (const float*)d_in[9];
    const float* b2  = (const float*)d_in[10];
    float* outF = (float*)d_out;

    char* ws = (char*)d_ws;
    size_t o = 0;
    f16* WqkvT = (f16*)(ws + o); o += (size_t)3072 * 1024 * 2;   // [3072][1024]
    f16* WoT   = (f16*)(ws + o); o += (size_t)1024 * 1024 * 2;
    f16* W1T   = (f16*)(ws + o); o += (size_t)4096 * 1024 * 2;
    f16* W2T   = (f16*)(ws + o); o += (size_t)1024 * 4096 * 2;
    f16* cb    = (f16*)(ws + o); o += (size_t)8192 * 1024 * 2;
    f16* qkvb  = (f16*)(ws + o); o += (size_t)8192 * 3072 * 2;
    f16* hb    = (f16*)(ws + o); o += (size_t)8192 * 4096 * 2;
    float* x2  = (float*)(ws + o); o += (size_t)8192 * 1024 * 4;

    dim3 tb(256), tg(512);
    // weight prep (Wq/Wk/Wv concatenated into [3072][1024])
    transpose_wt<<<dim3(32, 32), tb, 0, stream>>>(wq, WqkvT, 1024, 1024);
    transpose_wt<<<dim3(32, 32), tb, 0, stream>>>(wk, WqkvT + (size_t)1024 * 1024, 1024, 1024);
    transpose_wt<<<dim3(32, 32), tb, 0, stream>>>(wv, WqkvT + (size_t)2048 * 1024, 1024, 1024);
    transpose_wt<<<dim3(32, 32), tb, 0, stream>>>(wo, WoT, 1024, 1024);
    transpose_wt<<<dim3(128, 32), tb, 0, stream>>>(w1, W1T, 1024, 4096);
    transpose_wt<<<dim3(32, 128), tb, 0, stream>>>(w2, W2T, 4096, 1024);

    // c = LN1(x)
    ln_f16<<<8192, tb, 0, stream>>>(x, ln1, cb);
    // qkv = c @ [Wq|Wk|Wv]   (M=8192, N=3072, K=1024)
    gemm8<256, 0, 1024, 3072><<<384, tg, 0, stream>>>(cb, WqkvT, nullptr, nullptr,
                                                      nullptr, qkvb, 0.f);
    // attention core -> cb
    attn_f16<<<256, tb, 0, stream>>>(qkvb, 3072, cb);
    // x1 = x + 2*(attn @ Wo)  -> d_out
    gemm8<128, 2, 1024, 1024><<<256, tg, 0, stream>>>(cb, WoT, nullptr, x,
                                                      outF, nullptr, 2.0f);
    // MLP block 1
    ln_f16<<<8192, tb, 0, stream>>>(outF, ln2, cb);
    gemm8<256, 1, 1024, 4096><<<512, tg, 0, stream>>>(cb, W1T, b1, nullptr,
                                                      nullptr, hb, 0.f);
    gemm8<128, 3, 4096, 1024><<<256, tg, 0, stream>>>(hb, W2T, b2, outF,
                                                      x2, nullptr, 1.0f);
    // MLP block 2
    ln_f16<<<8192, tb, 0, stream>>>(x2, ln2, cb);
    gemm8<256, 1, 1024, 4096><<<512, tg, 0, stream>>>(cb, W1T, b1, nullptr,
                                                      nullptr, hb, 0.f);
    gemm8<128, 3, 4096, 1024><<<256, tg, 0, stream>>>(hb, W2T, b2, x2,
                                                      outF, nullptr, 1.0f);
}

// Round 7
// 632.614 us; speedup vs baseline: 1.0726x; 1.0726x over previous
//
#include <hip/hip_runtime.h>
#include <hip/hip_bf16.h>

typedef _Float16 f16;
typedef _Float16 f16x8 __attribute__((ext_vector_type(8)));
typedef _Float16 f16x4 __attribute__((ext_vector_type(4)));
typedef float    f32x4 __attribute__((ext_vector_type(4)));

#define MFMA16x16x32(a, b, c) __builtin_amdgcn_mfma_f32_16x16x32_f16(a, b, c, 0, 0, 0)

typedef __attribute__((address_space(1))) const void GASV;
typedef __attribute__((address_space(3))) void LASV;

#define WAIT_VM0   asm volatile("s_waitcnt vmcnt(0)" ::: "memory")
#define WAIT_VM6   asm volatile("s_waitcnt vmcnt(6)" ::: "memory")
#define WAIT_VM8   asm volatile("s_waitcnt vmcnt(8)" ::: "memory")
#define SB0        __builtin_amdgcn_sched_barrier(0)

__device__ inline float gelu_f(float x) {
    float z = 0.79788456080286535588f * (x + 0.044715f * x * x * x);
    float e = __expf(2.0f * z);
    float t = 1.0f - 2.0f / (e + 1.0f);
    return 0.5f * x * (1.0f + t);
}

// ---------------------------------------------------------------------------
// Weight transpose + fp32 -> f16 convert:  in[K][N] f32  ->  out[N][K] f16
// ---------------------------------------------------------------------------
__global__ __launch_bounds__(256) void transpose_wt(const float* __restrict__ in,
                                                    f16* __restrict__ out,
                                                    int K, int N) {
    __shared__ float tile[32][33];
    int n0 = blockIdx.x * 32, k0 = blockIdx.y * 32;
    int tx = threadIdx.x & 31, ty = threadIdx.x >> 5;  // 32 x 8
#pragma unroll
    for (int i = 0; i < 32; i += 8)
        tile[ty + i][tx] = in[(size_t)(k0 + ty + i) * N + n0 + tx];
    __syncthreads();
#pragma unroll
    for (int i = 0; i < 32; i += 8)
        out[(size_t)(n0 + ty + i) * K + k0 + tx] = (f16)tile[tx][ty + i];
}

// ---------------------------------------------------------------------------
// LayerNorm (use_bias=False): fp32 in -> f16 out, row length 1024
// ---------------------------------------------------------------------------
__global__ __launch_bounds__(256) void ln_f16(const float* __restrict__ x,
                                              const float* __restrict__ g,
                                              f16* __restrict__ out) {
    int row = blockIdx.x, t = threadIdx.x;
    float4 v = ((const float4*)(x + (size_t)row * 1024))[t];
    float s  = v.x + v.y + v.z + v.w;
    float s2 = v.x * v.x + v.y * v.y + v.z * v.z + v.w * v.w;
#pragma unroll
    for (int off = 1; off < 64; off <<= 1) {
        s  += __shfl_xor(s, off);
        s2 += __shfl_xor(s2, off);
    }
    __shared__ float red[8];
    int w = t >> 6, lane = t & 63;
    if (lane == 0) { red[w] = s; red[4 + w] = s2; }
    __syncthreads();
    s  = red[0] + red[1] + red[2] + red[3];
    s2 = red[4] + red[5] + red[6] + red[7];
    float mean = s * (1.0f / 1024.0f);
    float var  = s2 * (1.0f / 1024.0f) - mean * mean;
    float r = rsqrtf(var + 1e-6f);
    float4 gv = ((const float4*)g)[t];
    f16x4 ov;
    ov[0] = (f16)((v.x - mean) * r * gv.x);
    ov[1] = (f16)((v.y - mean) * r * gv.y);
    ov[2] = (f16)((v.z - mean) * r * gv.z);
    ov[3] = (f16)((v.w - mean) * r * gv.w);
    *(f16x4*)(out + (size_t)row * 1024 + t * 4) = ov;
}

// ---------------------------------------------------------------------------
// 4-phase/K-tile GEMM with ds-read software pipelining (1-phase lead).
// C[M,N] = A[M,K] @ Bt[N,K]^T, f16 in, fp32 acc. BN=256, BK=64,
// 512 threads = 8 waves (2 M x 4 N). BM=256 or 128. K, N compile-time.
// LDS: [2 bufs][AH+2 half-tiles][128x64 f16] + 16KB dummy tail sink.
// Swizzle (3-bit): phys_slot = slot ^ (row & 7); gload_lds linear dest +
//   inverse-swizzled global src (R4-verified: bank conflicts = 0).
// Per iter t (cur=t&1, nxt=cur^1) — each phase: [issue reads for NEXT
// phase's MFMA][MFMA on last phase's reads][barrier]. Counted lgkmcnt is
// compiler-auto (reg deps are 1 phase old; just-issued reads stay in
// flight). ONE barrier per phase (4/K-tile, was 8).
//   P0: rd fb23(cur);            MFMA faL x fb01
//   P1: rd faH(cur);             MFMA faL x fb23; vmcnt(0)  [tile t+1 landed]
//   P2: rd faL(nxt);             MFMA faH x fb01
//   P3: rd fb01(nxt); stage t+2; MFMA faH x fb23
// Hazards: reg-WAR — each slot refilled >=1 phase after last MFMA use
//   (fb23@P0 after P3-prev, faH@P1 after P3-prev, faL@P2 after P1,
//    fb01@P3 after P2). LDS-WAR — all buf[cur] reads confirmed (per-wave
//   lgkm) by end-P2 + barrier => stage(t+2)->buf[cur] at P3 safe.
//   LDS-RAW — tile t+1 staged P3(t-1), vmcnt(0)+barrier end-P1(t), first
//   read P2(t). Tail: kt>=NT stages go to dummy (vmcnt ledger exact).
// EPI: 0 = f16 out; 1 = f16 gelu(acc+bias); 2 = f32 resid + rscale*acc;
//      3 = f32 resid + acc + bias
// ---------------------------------------------------------------------------
template <int BM, int EPI, int K, int N>
__global__ __launch_bounds__(512, 2) void gemm8(
    const f16* __restrict__ A, const f16* __restrict__ Bt,
    const float* __restrict__ bias, const float* __restrict__ resid,
    float* __restrict__ outF, f16* __restrict__ outH, float rscale) {
    static_assert(BM == 256 || BM == 128, "BM");
    constexpr int AH   = BM / 128;      // # A half-tiles
    constexpr int MREP = BM / 32;       // per-wave M fragments
    constexpr int MH   = MREP / 2;
    constexpr int NT   = K / 64;

    __shared__ __align__(16) f16 lds[2][AH + 2][128 * 64];
    __shared__ __align__(16) f16 dummyb[8192];   // 16KB tail-stage sink

    const int t512 = threadIdx.x;
    const int lane = t512 & 63, w = t512 >> 6;
    const int l15 = lane & 15, lg = lane >> 4;
    const int wr = w >> 2, wc = w & 3;   // 2 x 4 wave grid

    // bijective XCD swizzle (nwg % 8 == 0 for all our launches)
    const int nwg = gridDim.x;
    const int bid = blockIdx.x;
    const int swz = (bid & 7) * (nwg >> 3) + (bid >> 3);
    constexpr int nbn = N / 256;
    const int bm = swz / nbn, bn = swz % nbn;
    const int m0 = bm * BM, n0 = bn * 256;

    // wave's operand halves
    const int ahalf = (BM == 256) ? wr : 0;
    const int arow0 = (BM == 256) ? 0 : wr * 64;
    const int bhalf = AH + (wc >> 1);
    const int brow0 = (wc & 1) * 64;

    // ---- stage a whole K-tile: (AH+2) halves x 2 gloads/thread ----
    auto stage_tile = [&](int kt) {
        const bool dum = (kt >= NT);
#pragma unroll
        for (int h = 0; h < AH + 2; ++h) {
            f16* dst0 = dum ? dummyb : &lds[kt & 1][h][0];
            const bool isA = (h < AH);
            const f16* Mat = isA ? A : Bt;
            const int rb = isA ? (m0 + h * 128) : (n0 + (h - AH) * 128);
#pragma unroll
            for (int u = 0; u < 2; ++u) {
                int c = u * 512 + t512;
                int cs = c ^ ((c >> 3) & 7);  // inverse-swizzled source chunk
                const f16* src = dum ? (A + (size_t)(c & 511) * 8)
                                     : (Mat + (size_t)(rb + (cs >> 3)) * K + kt * 64 + (cs & 7) * 8);
                __builtin_amdgcn_global_load_lds((GASV*)src, (LASV*)(dst0 + c * 8), 16, 0, 0);
            }
        }
    };
    // swizzled frag read: logical (buf, half, row-in-half, 16B slot)
    auto ldfrag = [&](int b, int half, int rh, int s) -> f16x8 {
        int ps = s ^ (rh & 7);
        return *(const f16x8*)(&lds[b][half][0] + rh * 64 + ps * 8);
    };

    f32x4 acc[MREP][4] = {};
    f16x8 faL[2][MH], faH[2][MH], fb[2][4];

    // ---- prologue: stage tiles 0,1; drain tile 0; preload faL+fb01(0) ----
    stage_tile(0);
    stage_tile(1);
    if (BM == 256) { WAIT_VM8; } else { WAIT_VM6; }
    SB0;
    __builtin_amdgcn_s_barrier();
#pragma unroll
    for (int ks = 0; ks < 2; ++ks) {
#pragma unroll
        for (int i = 0; i < MH; ++i)
            faL[ks][i] = ldfrag(0, ahalf, arow0 + i * 16 + l15, ks * 4 + lg);
#pragma unroll
        for (int j = 0; j < 2; ++j)
            fb[ks][j] = ldfrag(0, bhalf, brow0 + j * 16 + l15, ks * 4 + lg);
    }

    for (int t = 0; t < NT; ++t) {
        const int cur = t & 1, nxt = cur ^ 1;
        // -------- P0: rd fb23(cur); MFMA faL x fb01 --------
#pragma unroll
        for (int ks = 0; ks < 2; ++ks)
#pragma unroll
            for (int j = 2; j < 4; ++j)
                fb[ks][j] = ldfrag(cur, bhalf, brow0 + j * 16 + l15, ks * 4 + lg);
        SB0;
        __builtin_amdgcn_s_setprio(1);
#pragma unroll
        for (int ks = 0; ks < 2; ++ks)
#pragma unroll
            for (int i = 0; i < MH; ++i)
#pragma unroll
                for (int j = 0; j < 2; ++j)
                    acc[i][j] = MFMA16x16x32(faL[ks][i], fb[ks][j], acc[i][j]);
        __builtin_amdgcn_s_setprio(0);
        __builtin_amdgcn_s_barrier();
        // -------- P1: rd faH(cur); MFMA faL x fb23; vmcnt(0) --------
#pragma unroll
        for (int ks = 0; ks < 2; ++ks)
#pragma unroll
            for (int i = 0; i < MH; ++i)
                faH[ks][i] = ldfrag(cur, ahalf, arow0 + (MH + i) * 16 + l15, ks * 4 + lg);
        SB0;
        __builtin_amdgcn_s_setprio(1);
#pragma unroll
        for (int ks = 0; ks < 2; ++ks)
#pragma unroll
            for (int i = 0; i < MH; ++i)
#pragma unroll
                for (int j = 0; j < 2; ++j)
                    acc[i][2 + j] = MFMA16x16x32(faL[ks][i], fb[ks][2 + j], acc[i][2 + j]);
        __builtin_amdgcn_s_setprio(0);
        WAIT_VM0;   // tile t+1 fully landed (staged at P3 of t-1 / prologue)
        SB0;
        __builtin_amdgcn_s_barrier();
        // -------- P2: rd faL(nxt); MFMA faH x fb01 --------
#pragma unroll
        for (int ks = 0; ks < 2; ++ks)
#pragma unroll
            for (int i = 0; i < MH; ++i)
                faL[ks][i] = ldfrag(nxt, ahalf, arow0 + i * 16 + l15, ks * 4 + lg);
        SB0;
        __builtin_amdgcn_s_setprio(1);
#pragma unroll
        for (int ks = 0; ks < 2; ++ks)
#pragma unroll
            for (int i = 0; i < MH; ++i)
#pragma unroll
                for (int j = 0; j < 2; ++j)
                    acc[MH + i][j] = MFMA16x16x32(faH[ks][i], fb[ks][j], acc[MH + i][j]);
        __builtin_amdgcn_s_setprio(0);
        __builtin_amdgcn_s_barrier();
        // -------- P3: rd fb01(nxt); stage t+2; MFMA faH x fb23 --------
#pragma unroll
        for (int ks = 0; ks < 2; ++ks)
#pragma unroll
            for (int j = 0; j < 2; ++j)
                fb[ks][j] = ldfrag(nxt, bhalf, brow0 + j * 16 + l15, ks * 4 + lg);
        stage_tile(t + 2);
        SB0;
        __builtin_amdgcn_s_setprio(1);
#pragma unroll
        for (int ks = 0; ks < 2; ++ks)
#pragma unroll
            for (int i = 0; i < MH; ++i)
#pragma unroll
                for (int j = 0; j < 2; ++j)
                    acc[MH + i][2 + j] = MFMA16x16x32(faH[ks][i], fb[ks][2 + j], acc[MH + i][2 + j]);
        __builtin_amdgcn_s_setprio(0);
        __builtin_amdgcn_s_barrier();
    }

    // ---- epilogue ----
#pragma unroll
    for (int mi = 0; mi < MREP; ++mi) {
#pragma unroll
        for (int ni = 0; ni < 4; ++ni) {
            int colL = n0 + wc * 64 + ni * 16 + l15;
#pragma unroll
            for (int j = 0; j < 4; ++j) {
                int rowL = m0 + ((BM == 256) ? wr * 128 : wr * 64) + mi * 16 + lg * 4 + j;
                size_t idx = (size_t)rowL * N + colL;
                float vv = acc[mi][ni][j];
                if constexpr (EPI == 0) {
                    outH[idx] = (f16)vv;
                } else if constexpr (EPI == 1) {
                    vv += bias[colL];
                    outH[idx] = (f16)gelu_f(vv);
                } else if constexpr (EPI == 2) {
                    outF[idx] = resid[idx] + rscale * vv;
                } else {
                    outF[idx] = resid[idx] + vv + bias[colL];
                }
            }
        }
    }
}

// ---------------------------------------------------------------------------
// Fused attention: one block per (b,h). Full K (swizzled) + V^T (swizzled)
// resident in LDS. qkv packed [8192][3072]: q at col 0, k at 1024, v at 2048.
// ---------------------------------------------------------------------------
__global__ __launch_bounds__(256) void attn_f16(const f16* __restrict__ qkv,
                                                int ld, f16* __restrict__ o) {
    __shared__ __align__(16) f16 Ks[512 * 64];
    __shared__ __align__(16) f16 Vt[64 * 512];
    __shared__ __align__(16) f16 Ps[4][16 * 32];

    const int t = threadIdx.x, lane = t & 63, w = t >> 6;
    const int l15 = lane & 15, lg = lane >> 4;
    const int bh = blockIdx.x, b = bh >> 4, h = bh & 15;
    const f16* qg = qkv + (size_t)(b * 512) * ld + h * 64;
    const f16* kg = qg + 1024;
    const f16* vg = qg + 2048;

#pragma unroll
    for (int i = 0; i < 16; ++i) {
        int c = i * 256 + t, r = c >> 3, s = c & 7;
        f16x8 val = *(const f16x8*)(kg + (size_t)r * ld + s * 8);
        *(f16x8*)((char*)Ks + r * 128 + ((s ^ (r & 7)) * 16)) = val;
    }
#pragma unroll
    for (int i = 0; i < 16; ++i) {
        int c = i * 256 + t, r = c >> 3, s = c & 7;
        f16x8 val = *(const f16x8*)(vg + (size_t)r * ld + s * 8);
#pragma unroll
        for (int dd = 0; dd < 8; ++dd) {
            int d = s * 8 + dd;
            *(f16*)((char*)Vt + d * 1024 + ((r * 2) ^ ((d & 7) << 4))) = val[dd];
        }
    }
    __syncthreads();

    for (int it = 0; it < 8; ++it) {
        int q0 = it * 64 + w * 16;
        f16x8 aq[2];
#pragma unroll
        for (int kk = 0; kk < 2; ++kk)
            aq[kk] = *(const f16x8*)(qg + (size_t)(q0 + l15) * ld + kk * 32 + lg * 8);

        f32x4 sc[32] = {};
#pragma unroll
        for (int jt = 0; jt < 32; ++jt) {
#pragma unroll
            for (int kk = 0; kk < 2; ++kk) {
                int row = jt * 16 + l15;
                f16x8 bk = *(const f16x8*)((char*)Ks + row * 128 + (((kk * 4 + lg) ^ (l15 & 7)) * 16));
                sc[jt] = MFMA16x16x32(aq[kk], bk, sc[jt]);
            }
        }

        float inv_sum[4];
#pragma unroll
        for (int r4 = 0; r4 < 4; ++r4) {
            float m = sc[0][r4];
#pragma unroll
            for (int jt = 1; jt < 32; ++jt) m = fmaxf(m, sc[jt][r4]);
#pragma unroll
            for (int off = 1; off < 16; off <<= 1) m = fmaxf(m, __shfl_xor(m, off));
            float sum = 0.0f;
#pragma unroll
            for (int jt = 0; jt < 32; ++jt) {
                float p = __expf((sc[jt][r4] - m) * 0.125f);
                sc[jt][r4] = p;
                sum += p;
            }
#pragma unroll
            for (int off = 1; off < 16; off <<= 1) sum += __shfl_xor(sum, off);
            inv_sum[r4] = 1.0f / sum;
        }

        f32x4 oa[4] = {};
        f16* myPs = &Ps[w][0];
#pragma unroll
        for (int u = 0; u < 16; ++u) {
#pragma unroll
            for (int half = 0; half < 2; ++half) {
                int jt = 2 * u + half;
#pragma unroll
                for (int r4 = 0; r4 < 4; ++r4) {
                    int row = lg * 4 + r4;
                    int colb = (half * 16 + l15) * 2;
                    *(f16*)((char*)myPs + row * 64 + (colb ^ (((row >> 1) & 3) << 4))) =
                        (f16)sc[jt][r4];
                }
            }
            f16x8 pa = *(const f16x8*)((char*)myPs + l15 * 64 + ((lg ^ ((l15 >> 1) & 3)) * 16));
#pragma unroll
            for (int ct = 0; ct < 4; ++ct) {
                int vrow = ct * 16 + l15;
                f16x8 bv = *(const f16x8*)((char*)Vt + vrow * 1024 + (((u * 4 + lg) ^ (vrow & 7)) * 16));
                oa[ct] = MFMA16x16x32(pa, bv, oa[ct]);
            }
        }

#pragma unroll
        for (int ct = 0; ct < 4; ++ct)
#pragma unroll
            for (int j = 0; j < 4; ++j) {
                int row = q0 + lg * 4 + j;
                int col = h * 64 + ct * 16 + l15;
                o[(size_t)(b * 512 + row) * 1024 + col] = (f16)(oa[ct][j] * inv_sum[j]);
            }
    }
}

// ---------------------------------------------------------------------------
extern "C" void kernel_launch(void* const* d_in, const int* in_sizes, int n_in,
                              void* d_out, int out_size, void* d_ws, size_t ws_size,
                              hipStream_t stream) {
    (void)in_sizes; (void)n_in; (void)out_size; (void)ws_size;
    const float* x   = (const float*)d_in[0];
    const float* wq  = (const float*)d_in[1];
    const float* wk  = (const float*)d_in[2];
    const float* wv  = (const float*)d_in[3];
    const float* wo  = (const float*)d_in[4];
    const float* ln1 = (const float*)d_in[5];
    const float* ln2 = (const float*)d_in[6];
    const float* w1  = (const float*)d_in[7];
    const float* b1  = (const float*)d_in[8];
    const float* w2  = (const float*)d_in[9];
    const float* b2  = (const float*)d_in[10];
    float* outF = (float*)d_out;

    char* ws = (char*)d_ws;
    size_t o = 0;
    f16* WqkvT = (f16*)(ws + o); o += (size_t)3072 * 1024 * 2;   // [3072][1024]
    f16* WoT   = (f16*)(ws + o); o += (size_t)1024 * 1024 * 2;
    f16* W1T   = (f16*)(ws + o); o += (size_t)4096 * 1024 * 2;
    f16* W2T   = (f16*)(ws + o); o += (size_t)1024 * 4096 * 2;
    f16* cb    = (f16*)(ws + o); o += (size_t)8192 * 1024 * 2;
    f16* qkvb  = (f16*)(ws + o); o += (size_t)8192 * 3072 * 2;
    f16* hb    = (f16*)(ws + o); o += (size_t)8192 * 4096 * 2;
    float* x2  = (float*)(ws + o); o += (size_t)8192 * 1024 * 4;

    dim3 tb(256), tg(512);
    // weight prep (Wq/Wk/Wv concatenated into [3072][1024])
    transpose_wt<<<dim3(32, 32), tb, 0, stream>>>(wq, WqkvT, 1024, 1024);
    transpose_wt<<<dim3(32, 32), tb, 0, stream>>>(wk, WqkvT + (size_t)1024 * 1024, 1024, 1024);
    transpose_wt<<<dim3(32, 32), tb, 0, stream>>>(wv, WqkvT + (size_t)2048 * 1024, 1024, 1024);
    transpose_wt<<<dim3(32, 32), tb, 0, stream>>>(wo, WoT, 1024, 1024);
    transpose_wt<<<dim3(128, 32), tb, 0, stream>>>(w1, W1T, 1024, 4096);
    transpose_wt<<<dim3(32, 128), tb, 0, stream>>>(w2, W2T, 4096, 1024);

    // c = LN1(x)
    ln_f16<<<8192, tb, 0, stream>>>(x, ln1, cb);
    // qkv = c @ [Wq|Wk|Wv]   (M=8192, N=3072, K=1024)
    gemm8<256, 0, 1024, 3072><<<384, tg, 0, stream>>>(cb, WqkvT, nullptr, nullptr,
                                                      nullptr, qkvb, 0.f);
    // attention core -> cb
    attn_f16<<<256, tb, 0, stream>>>(qkvb, 3072, cb);
    // x1 = x + 2*(attn @ Wo)  -> d_out
    gemm8<128, 2, 1024, 1024><<<256, tg, 0, stream>>>(cb, WoT, nullptr, x,
                                                      outF, nullptr, 2.0f);
    // MLP block 1
    ln_f16<<<8192, tb, 0, stream>>>(outF, ln2, cb);
    gemm8<256, 1, 1024, 4096><<<512, tg, 0, stream>>>(cb, W1T, b1, nullptr,
                                                      nullptr, hb, 0.f);
    gemm8<128, 3, 4096, 1024><<<256, tg, 0, stream>>>(hb, W2T, b2, outF,
                                                      x2, nullptr, 1.0f);
    // MLP block 2
    ln_f16<<<8192, tb, 0, stream>>>(x2, ln2, cb);
    gemm8<256, 1, 1024, 4096><<<512, tg, 0, stream>>>(cb, W1T, b1, nullptr,
                                                      nullptr, hb, 0.f);
    gemm8<128, 3, 4096, 1024><<<256, tg, 0, stream>>>(hb, W2T, b2, x2,
                                                      outF, nullptr, 1.0f);
}